// Round 4
// baseline (260.718 us; speedup 1.0000x reference)
//
#include <hip/hip_runtime.h>
#include <hip/hip_bf16.h>
#include <math.h>

#define B_  4096
#define F_  100
#define H_  128
#define H2_ 64
#define NG  16     // feature groups

typedef float    f32x4  __attribute__((ext_vector_type(4)));
typedef __bf16   bf16x8 __attribute__((ext_vector_type(8)));
typedef __bf16   bf16x2 __attribute__((ext_vector_type(2)));
typedef unsigned int uint4v __attribute__((ext_vector_type(4)));

__device__ __forceinline__ float el(float v) { return v > 0.f ? v : __expf(v) - 1.f; }

__device__ __forceinline__ unsigned pkpair(float lo, float hi) {
  bf16x2 t; t[0] = (__bf16)lo; t[1] = (__bf16)hi;
  return __builtin_bit_cast(unsigned, t);
}

// ================= fused prep ==============================================================
// bid 0..299   : W-pack (LDS-free). wb layout per (f,layer): 8-bf16 block (n,c) [k=8c..8c+7]
//                at byte (n*256 + c*16) ^ ((n&7)<<4)   (identical to R3 layout)
// bid 300..499 : per (f,t): wv = Wh1·Wh2 (LDS only) -> u[f,t,k] = W4[f,k,:]·wv ;
//                c2[f,t] = b4[f]·wv + bh1·Wh2 + bh2
// bid 500..515 : xT[f][b] = x[b][f]
__global__ __launch_bounds__(256) void prep(
    const float* __restrict__ W2, const float* __restrict__ W3, const float* __restrict__ W4,
    const float* __restrict__ Wh1, const float* __restrict__ bh1,
    const float* __restrict__ Wh2, const float* __restrict__ bh2,
    const float* __restrict__ x, const float* __restrict__ b4,
    __bf16* __restrict__ wb, float* __restrict__ u, float* __restrict__ c2,
    float* __restrict__ xT) {
  const int bid = blockIdx.x;
  const int tid = threadIdx.x;
  if (bid < 300) {
    const int f = bid / 3, ly = bid % 3;
    const float* src = (ly == 0 ? W2 : (ly == 1 ? W3 : W4)) + (size_t)f * (H_ * H_);
    __bf16* wo = wb + (size_t)bid * (H_ * H_);
    #pragma unroll
    for (int it = 0; it < 8; ++it) {
      int idx = it * 256 + tid;
      int c = idx >> 7, n = idx & 127;          // lanes -> consecutive n: coalesced reads
      bf16x8 o;
      #pragma unroll
      for (int j = 0; j < 8; ++j) o[j] = (__bf16)src[(8 * c + j) * H_ + n];
      int boff = ((n << 8) + (c << 4)) ^ ((n & 7) << 4);
      *(bf16x8*)((char*)wo + boff) = o;
    }
  } else if (bid < 500) {
    const int hb = bid - 300, f = hb >> 1;
    __shared__ __align__(16) float wh2s[H2_];
    __shared__ __align__(16) float wvs[H_];
    if (tid < 64) wh2s[tid] = Wh2[hb * H2_ + tid];
    __syncthreads();
    {  // wv fold
      const int h = tid >> 1, half = tid & 1;
      const f32x4* rw = (const f32x4*)(Wh1 + ((size_t)hb * H_ + h) * H2_ + half * 32);
      const f32x4* bvp = (const f32x4*)&wh2s[half * 32];
      float s = 0.f;
      #pragma unroll
      for (int m4 = 0; m4 < 8; ++m4) {
        f32x4 av = rw[m4], bv = bvp[m4];
        s += av[0]*bv[0] + av[1]*bv[1] + av[2]*bv[2] + av[3]*bv[3];
      }
      s += __shfl_xor(s, 1);
      if (!half) wvs[h] = s;
    }
    __syncthreads();
    {  // u = W4-row · wv
      const int k = tid >> 1, half = tid & 1;
      const f32x4* rw = (const f32x4*)(W4 + ((size_t)f * H_ + k) * H_ + half * 64);
      const f32x4* bvp = (const f32x4*)&wvs[half * 64];
      float s = 0.f;
      #pragma unroll
      for (int m4 = 0; m4 < 16; ++m4) {
        f32x4 av = rw[m4], bv = bvp[m4];
        s += av[0]*bv[0] + av[1]*bv[1] + av[2]*bv[2] + av[3]*bv[3];
      }
      s += __shfl_xor(s, 1);
      if (!half) u[(size_t)hb * H_ + k] = s;
    }
    if (tid < 64) {  // c2 = b4·wv + bh1·Wh2 + bh2
      float p = b4[(size_t)f * H_ + tid] * wvs[tid]
              + b4[(size_t)f * H_ + 64 + tid] * wvs[64 + tid]
              + bh1[hb * H2_ + tid] * wh2s[tid];
      #pragma unroll
      for (int off = 32; off > 0; off >>= 1) p += __shfl_xor(p, off);
      if (tid == 0) c2[hb] = p + bh2[hb];
    }
  } else {
    const int r = (bid - 500) * 256 + tid;
    const f32x4* src = (const f32x4*)(x + (size_t)r * F_);
    #pragma unroll 5
    for (int j4 = 0; j4 < F_ / 4; ++j4) {
      f32x4 v = src[j4];
      #pragma unroll
      for (int c = 0; c < 4; ++c) xT[(size_t)(j4 * 4 + c) * B_ + r] = v[c];
    }
  }
}

// A-fragment read (wT in LDS, swizzled): lane row n = mt*16+lc, k = ks*32+8g..+7 contiguous.
__device__ __forceinline__ bf16x8 lda(const __bf16* buf, int mt, int ks, int lc, int g) {
  int rown = mt * 16 + lc;
  int boff = (rown << 8) + (ks << 6) + (g << 4);
  boff ^= (rown & 7) << 4;
  return *(const bf16x8*)((const char*)buf + boff);
}

// B-fragment via intra-lane-class exchange of previous layer's packed output.
__device__ __forceinline__ bf16x8 exch(const unsigned (&pks)[8][2], int ks, int s0l, bool hi5) {
  unsigned a0 = __shfl(pks[2*ks][0],   s0l,      64);
  unsigned a1 = __shfl(pks[2*ks][1],   s0l,      64);
  unsigned b0 = __shfl(pks[2*ks+1][0], s0l,      64);
  unsigned b1 = __shfl(pks[2*ks+1][1], s0l,      64);
  unsigned c0 = __shfl(pks[2*ks][0],   s0l + 16, 64);
  unsigned c1 = __shfl(pks[2*ks][1],   s0l + 16, 64);
  unsigned d0 = __shfl(pks[2*ks+1][0], s0l + 16, 64);
  unsigned d1 = __shfl(pks[2*ks+1][1], s0l + 16, 64);
  uint4v uu;
  uu[0] = hi5 ? b0 : a0;  uu[1] = hi5 ? b1 : a1;
  uu[2] = hi5 ? d0 : c0;  uu[3] = hi5 ? d1 : c1;
  return __builtin_bit_cast(bf16x8, uu);
}

#define PHASE_SYNC() do {                                                   \
    asm volatile("s_waitcnt lgkmcnt(0)" ::: "memory");                      \
    __builtin_amdgcn_s_barrier();                                           \
    if (item + 2 < nitems) {                                                \
      stage(item + 2);                                                      \
      asm volatile("s_waitcnt vmcnt(8)" ::: "memory");                      \
    } else {                                                                \
      asm volatile("s_waitcnt vmcnt(0)" ::: "memory");                      \
    }                                                                       \
    __builtin_amdgcn_s_barrier();                                           \
    ++item;                                                                 \
  } while (0)

__global__ __launch_bounds__(256, 2) void nam_mfma(
    const float* __restrict__ xT, const int* __restrict__ a,
    const float* __restrict__ W1, const float* __restrict__ b1,
    const float* __restrict__ b2, const float* __restrict__ b3, const float* __restrict__ b4,
    const float* __restrict__ u, const float* __restrict__ c2,
    const __bf16* __restrict__ wb,
    float* __restrict__ pbb, float* __restrict__ py) {
  __shared__ __align__(1024) __bf16 wlds[2][H_ * H_];   // 2 x 32KB double buffer

  const int tid = threadIdx.x;
  const int l  = tid & 63;
  const int lc = l & 15, g = l >> 4;
  const int bid = blockIdx.x;
  const int bx = bid >> 4, by = bid & 15;               // bid%8 == by%8 -> group pinned to XCD
  const int rw = bx * 128 + (tid >> 6) * 32;            // wave's 32-row base (4 waves)
  const int f0 = (by * F_) / NG, f1 = ((by + 1) * F_) / NG;
  const int nitems = 3 * (f1 - f0);

  const int row0 = rw + lc, row1 = rw + 16 + lc;
  const int ta0 = a[row0], ta1 = a[row1];
  const int s0l = lc + ((l & 16) << 1);
  const bool hi5 = (l & 32) != 0;

  f32x4 acc[8][2], acc4[8][2];
  unsigned pk[2][8][2];
  const f32x4 z = {0.f, 0.f, 0.f, 0.f};
  #pragma unroll
  for (int mt = 0; mt < 8; ++mt) { acc4[mt][0] = z; acc4[mt][1] = z; }
  float ysum0 = 0.f, ysum1 = 0.f;

  auto stage = [&](int it) {
    const char* gsrc = (const char*)(wb + (size_t)(f0 * 3 + it) * (H_ * H_));
    char* ldst = (char*)&wlds[it & 1][0];
    #pragma unroll
    for (int r = 0; r < 8; ++r) {
      int off = (tid + 256 * r) * 16;
      __builtin_amdgcn_global_load_lds(
          (const __attribute__((address_space(1))) void*)(gsrc + off),
          (__attribute__((address_space(3))) void*)(ldst + off), 16, 0, 0);
    }
  };

  stage(0); stage(1);
  asm volatile("s_waitcnt vmcnt(8)" ::: "memory");
  __builtin_amdgcn_s_barrier();

  int item = 0;
  for (int fi = f0; fi < f1; ++fi) {
    // ================= phase 0: h2 = elu(h1 W2 + b2); h1 built on the fly ================
    {
      const __bf16* buf = wlds[item & 1];
      #pragma unroll
      for (int mt = 0; mt < 8; ++mt) { acc[mt][0] = z; acc[mt][1] = z; }
      const float* w1p = W1 + (size_t)fi * H_;
      const float* b1p = b1 + (size_t)fi * H_;
      float xs0 = xT[(size_t)fi * B_ + row0];
      float xs1 = xT[(size_t)fi * B_ + row1];
      #pragma unroll
      for (int ks = 0; ks < 4; ++ks) {
        int k0 = ks * 32 + 8 * g;
        f32x4 wa  = *(const f32x4*)(w1p + k0);
        f32x4 wb2 = *(const f32x4*)(w1p + k0 + 4);
        f32x4 ba  = *(const f32x4*)(b1p + k0);
        f32x4 bb2 = *(const f32x4*)(b1p + k0 + 4);
        bf16x8 bf0, bf1;
        #pragma unroll
        for (int e = 0; e < 4; ++e) {
          bf0[e]     = (__bf16)el(xs0 * wa[e]  + ba[e]);
          bf0[e + 4] = (__bf16)el(xs0 * wb2[e] + bb2[e]);
          bf1[e]     = (__bf16)el(xs1 * wa[e]  + ba[e]);
          bf1[e + 4] = (__bf16)el(xs1 * wb2[e] + bb2[e]);
        }
        #pragma unroll
        for (int mt = 0; mt < 8; ++mt) {
          bf16x8 av = lda(buf, mt, ks, lc, g);
          acc[mt][0] = __builtin_amdgcn_mfma_f32_16x16x32_bf16(av, bf0, acc[mt][0], 0, 0, 0);
          acc[mt][1] = __builtin_amdgcn_mfma_f32_16x16x32_bf16(av, bf1, acc[mt][1], 0, 0, 0);
        }
      }
      const float* bp = b2 + (size_t)fi * H_;
      #pragma unroll
      for (int mt = 0; mt < 8; ++mt) {
        f32x4 bia = *(const f32x4*)(bp + mt * 16 + 4 * g);
        #pragma unroll
        for (int nt = 0; nt < 2; ++nt) {
          f32x4 t = acc[mt][nt];
          float t0 = el(t[0] + bia[0]), t1 = el(t[1] + bia[1]);
          float t2 = el(t[2] + bia[2]), t3 = el(t[3] + bia[3]);
          pk[nt][mt][0] = pkpair(t0, t1);
          pk[nt][mt][1] = pkpair(t2, t3);
        }
      }
    }
    PHASE_SYNC();
    // ================= phase 1: h3 = elu(h2 W3 + b3), + y-dot with u =====================
    {
      const __bf16* buf = wlds[item & 1];
      #pragma unroll
      for (int mt = 0; mt < 8; ++mt) { acc[mt][0] = z; acc[mt][1] = z; }
      #pragma unroll
      for (int ks = 0; ks < 4; ++ks) {
        bf16x8 bf0 = exch(pk[0], ks, s0l, hi5);
        bf16x8 bf1 = exch(pk[1], ks, s0l, hi5);
        #pragma unroll
        for (int mt = 0; mt < 8; ++mt) {
          bf16x8 av = lda(buf, mt, ks, lc, g);
          acc[mt][0] = __builtin_amdgcn_mfma_f32_16x16x32_bf16(av, bf0, acc[mt][0], 0, 0, 0);
          acc[mt][1] = __builtin_amdgcn_mfma_f32_16x16x32_bf16(av, bf1, acc[mt][1], 0, 0, 0);
        }
      }
      const float* bp = b3 + (size_t)fi * H_;
      const float* u0 = u + (size_t)(fi * 2 + ta0) * H_;
      const float* u1 = u + (size_t)(fi * 2 + ta1) * H_;
      float yd0 = 0.f, yd1 = 0.f;
      #pragma unroll
      for (int mt = 0; mt < 8; ++mt) {
        int n = mt * 16 + 4 * g;
        f32x4 bia = *(const f32x4*)(bp + n);
        f32x4 uv0 = *(const f32x4*)(u0 + n);
        f32x4 uv1 = *(const f32x4*)(u1 + n);
        {
          f32x4 t = acc[mt][0];
          float t0 = el(t[0] + bia[0]), t1 = el(t[1] + bia[1]);
          float t2 = el(t[2] + bia[2]), t3 = el(t[3] + bia[3]);
          pk[0][mt][0] = pkpair(t0, t1);
          pk[0][mt][1] = pkpair(t2, t3);
          yd0 += t0*uv0[0] + t1*uv0[1] + t2*uv0[2] + t3*uv0[3];
        }
        {
          f32x4 t = acc[mt][1];
          float t0 = el(t[0] + bia[0]), t1 = el(t[1] + bia[1]);
          float t2 = el(t[2] + bia[2]), t3 = el(t[3] + bia[3]);
          pk[1][mt][0] = pkpair(t0, t1);
          pk[1][mt][1] = pkpair(t2, t3);
          yd1 += t0*uv1[0] + t1*uv1[1] + t2*uv1[2] + t3*uv1[3];
        }
      }
      ysum0 += yd0 + (g == 0 ? c2[fi * 2 + ta0] : 0.f);
      ysum1 += yd1 + (g == 0 ? c2[fi * 2 + ta1] : 0.f);
    }
    PHASE_SYNC();
    // ================= phase 2: GEMM4 accumulates across features into acc4 ==============
    {
      const __bf16* buf = wlds[item & 1];
      #pragma unroll
      for (int ks = 0; ks < 4; ++ks) {
        bf16x8 bf0 = exch(pk[0], ks, s0l, hi5);
        bf16x8 bf1 = exch(pk[1], ks, s0l, hi5);
        #pragma unroll
        for (int mt = 0; mt < 8; ++mt) {
          bf16x8 av = lda(buf, mt, ks, lc, g);
          acc4[mt][0] = __builtin_amdgcn_mfma_f32_16x16x32_bf16(av, bf0, acc4[mt][0], 0, 0, 0);
          acc4[mt][1] = __builtin_amdgcn_mfma_f32_16x16x32_bf16(av, bf1, acc4[mt][1], 0, 0, 0);
        }
      }
    }
    PHASE_SYNC();
  }

  // ---- bb = acc4 + sum_{f in group} b4[f]
  f32x4 s4[8];
  #pragma unroll
  for (int mt = 0; mt < 8; ++mt) s4[mt] = z;
  for (int f = f0; f < f1; ++f) {
    #pragma unroll
    for (int mt = 0; mt < 8; ++mt)
      s4[mt] += *(const f32x4*)(b4 + (size_t)f * H_ + mt * 16 + 4 * g);
  }
  #pragma unroll
  for (int mt = 0; mt < 8; ++mt) {
    int n = mt * 16 + 4 * g;
    *(f32x4*)(pbb + ((size_t)by * B_ + row0) * H_ + n) = acc4[mt][0] + s4[mt];
    *(f32x4*)(pbb + ((size_t)by * B_ + row1) * H_ + n) = acc4[mt][1] + s4[mt];
  }
  float y0 = ysum0 + __shfl_xor(ysum0, 16, 64); y0 += __shfl_xor(y0, 32, 64);
  float y1 = ysum1 + __shfl_xor(ysum1, 16, 64); y1 += __shfl_xor(y1, 32, 64);
  if (g == 0) {
    py[by * B_ + row0] = y0;
    py[by * B_ + row1] = y1;
  }
}

// ================= final reduction over the NG feature groups =============================
__global__ __launch_bounds__(256) void reduce_out(const float* __restrict__ pbb,
                                                  const float* __restrict__ py,
                                                  float* __restrict__ out) {
  const int idx = blockIdx.x * 256 + threadIdx.x;
  if (idx < B_ * H_) {
    float s = 0.f;
    #pragma unroll
    for (int g = 0; g < NG; ++g) s += pbb[(size_t)g * (B_ * H_) + idx];
    out[idx] = s;
  } else if (idx < B_ * H_ + B_) {
    const int b = idx - B_ * H_;
    float s = 0.f;
    #pragma unroll
    for (int g = 0; g < NG; ++g) s += py[g * B_ + b];
    out[idx] = s;
  }
}

extern "C" void kernel_launch(void* const* d_in, const int* in_sizes, int n_in,
                              void* d_out, int out_size, void* d_ws, size_t ws_size,
                              hipStream_t stream) {
  const float* x   = (const float*)d_in[0];
  const int*   aa  = (const int*)d_in[1];
  const float* W1  = (const float*)d_in[2];
  const float* b1  = (const float*)d_in[3];
  const float* W2  = (const float*)d_in[4];
  const float* b2  = (const float*)d_in[5];
  const float* W3  = (const float*)d_in[6];
  const float* b3  = (const float*)d_in[7];
  const float* W4  = (const float*)d_in[8];
  const float* b4  = (const float*)d_in[9];
  const float* Wh1 = (const float*)d_in[10];
  const float* bh1 = (const float*)d_in[11];
  const float* Wh2 = (const float*)d_in[12];
  const float* bh2 = (const float*)d_in[13];
  float* out = (float*)d_out;

  char* ws = (char*)d_ws;
  float*  u   = (float*)(ws + 0);              // 102,400 B
  float*  c2p = (float*)(ws + 102400);         // 800 B
  __bf16* wbp = (__bf16*)(ws + 103424);        // 9,830,400 B
  float*  xT  = (float*)(ws + 9933824);        // 1,638,400 B
  float*  py  = (float*)(ws + 11572224);       // 262,144 B
  float*  pbb = (float*)(ws + 11834368);       // 33,554,432 B

  prep<<<dim3(516), dim3(256), 0, stream>>>(W2, W3, W4, Wh1, bh1, Wh2, bh2, x, b4,
                                            wbp, u, c2p, xT);
  nam_mfma<<<dim3(512), dim3(256), 0, stream>>>(
      xT, aa, W1, b1, b2, b3, b4, u, c2p, wbp, pbb, py);
  reduce_out<<<dim3((B_ * H_ + B_ + 255) / 256), dim3(256), 0, stream>>>(pbb, py, out);
}

// Round 5
// 227.388 us; speedup vs baseline: 1.1466x; 1.1466x over previous
//
#include <hip/hip_runtime.h>
#include <hip/hip_bf16.h>
#include <math.h>

#define B_  4096
#define F_  100
#define H_  128
#define H2_ 64
#define NG  16     // feature groups

typedef float    f32x4  __attribute__((ext_vector_type(4)));
typedef __bf16   bf16x8 __attribute__((ext_vector_type(8)));
typedef __bf16   bf16x2 __attribute__((ext_vector_type(2)));
typedef unsigned int uint4v __attribute__((ext_vector_type(4)));

__device__ __forceinline__ float el(float v) { return v > 0.f ? v : __expf(v) - 1.f; }

__device__ __forceinline__ unsigned pkpair(float lo, float hi) {
  bf16x2 t; t[0] = (__bf16)lo; t[1] = (__bf16)hi;
  return __builtin_bit_cast(unsigned, t);
}

// ================= fused prep ==============================================================
// bid 0..299   : W-pack, both-sides coalesced. wb layout per (f,layer): 8-bf16 block (n,c)
//                [k=8c..8c+7] at byte (n*256 + c*16) ^ ((n&7)<<4)  (same layout as R3/R4).
//                Path: coalesced f32x4 reads -> LDS tile -> swizzled chunks in regs ->
//                LDS scatter (aliased onto tile) -> LINEAR coalesced 16B global writes.
// bid 300..499 : head fold wv[f,t,h] = Wh1·Wh2 ; cb = bh1·Wh2 + bh2   (R3 version)
// bid 500..515 : xT[f][b] = x[b][f]
__global__ __launch_bounds__(256) void prep(
    const float* __restrict__ W2, const float* __restrict__ W3, const float* __restrict__ W4,
    const float* __restrict__ Wh1, const float* __restrict__ bh1,
    const float* __restrict__ Wh2, const float* __restrict__ bh2,
    const float* __restrict__ x,
    __bf16* __restrict__ wb, float* __restrict__ wv, float* __restrict__ cb,
    float* __restrict__ xT) {
  const int bid = blockIdx.x;
  const int tid = threadIdx.x;
  if (bid < 300) {
    __shared__ __align__(16) float tile[128 * 132];     // 67,584 B
    const int f = bid / 3, ly = bid % 3;
    const float* src = (ly == 0 ? W2 : (ly == 1 ? W3 : W4)) + (size_t)f * (H_ * H_);
    #pragma unroll
    for (int r = 0; r < 16; ++r) {
      int i4 = tid + 256 * r;
      int k = i4 >> 5, n0 = (i4 & 31) << 2;
      *(f32x4*)&tile[k * 132 + n0] = *(const f32x4*)(src + ((size_t)i4 << 2));
    }
    __syncthreads();
    bf16x8 o[8]; int bo[8];
    #pragma unroll
    for (int wq = 0; wq < 8; ++wq) {
      int idx = tid + 256 * wq;
      int n = idx >> 4, c = idx & 15;
      #pragma unroll
      for (int j = 0; j < 8; ++j) o[wq][j] = (__bf16)tile[(8 * c + j) * 132 + n];
      bo[wq] = ((n << 8) + (c << 4)) ^ ((n & 7) << 4);
    }
    __syncthreads();          // all tile reads done; safe to overwrite via alias
    char* obuf = (char*)tile; // low 32 KB reused as swizzled output staging
    #pragma unroll
    for (int wq = 0; wq < 8; ++wq) *(bf16x8*)(obuf + bo[wq]) = o[wq];
    __syncthreads();
    char* wo = (char*)(wb + (size_t)bid * (H_ * H_));
    #pragma unroll
    for (int w = 0; w < 8; ++w) {
      int off = (tid + 256 * w) * 16;
      *(bf16x8*)(wo + off) = *(const bf16x8*)(obuf + off);   // coalesced linear writes
    }
  } else if (bid < 500) {
    const int hb = bid - 300;          // f*2 + t
    __shared__ __align__(16) float w2s[H2_];
    if (tid < 64) w2s[tid] = Wh2[hb * H2_ + tid];
    __syncthreads();
    const int h = tid >> 1, half = tid & 1;
    const f32x4* rw = (const f32x4*)(Wh1 + ((size_t)hb * H_ + h) * H2_ + half * 32);
    const f32x4* bvp = (const f32x4*)&w2s[half * 32];
    float s = 0.f;
    #pragma unroll
    for (int m4 = 0; m4 < 8; ++m4) {
      f32x4 av = rw[m4], bv = bvp[m4];
      s += av[0]*bv[0] + av[1]*bv[1] + av[2]*bv[2] + av[3]*bv[3];
    }
    s += __shfl_xor(s, 1);
    if (!half) wv[hb * H_ + h] = s;
    if (tid < 64) {
      float p = bh1[hb * H2_ + tid] * w2s[tid];
      #pragma unroll
      for (int off = 32; off > 0; off >>= 1) p += __shfl_xor(p, off);
      if (tid == 0) cb[hb] = p + bh2[hb];
    }
  } else {
    const int r = (bid - 500) * 256 + tid;
    const f32x4* src = (const f32x4*)(x + (size_t)r * F_);
    #pragma unroll 5
    for (int j4 = 0; j4 < F_ / 4; ++j4) {
      f32x4 v = src[j4];
      #pragma unroll
      for (int c = 0; c < 4; ++c) xT[(size_t)(j4 * 4 + c) * B_ + r] = v[c];
    }
  }
}

// A-fragment read (wT in LDS, swizzled): lane row n = mt*16+lc, k = ks*32+8g..+7 contiguous.
__device__ __forceinline__ bf16x8 lda(const __bf16* buf, int mt, int ks, int lc, int g) {
  int rown = mt * 16 + lc;
  int boff = (rown << 8) + (ks << 6) + (g << 4);
  boff ^= (rown & 7) << 4;
  return *(const bf16x8*)((const char*)buf + boff);
}

// B-fragment via intra-lane-class exchange of previous layer's packed output.
__device__ __forceinline__ bf16x8 exch(const unsigned (&pks)[8][2], int ks, int s0l, bool hi5) {
  unsigned a0 = __shfl(pks[2*ks][0],   s0l,      64);
  unsigned a1 = __shfl(pks[2*ks][1],   s0l,      64);
  unsigned b0 = __shfl(pks[2*ks+1][0], s0l,      64);
  unsigned b1 = __shfl(pks[2*ks+1][1], s0l,      64);
  unsigned c0 = __shfl(pks[2*ks][0],   s0l + 16, 64);
  unsigned c1 = __shfl(pks[2*ks][1],   s0l + 16, 64);
  unsigned d0 = __shfl(pks[2*ks+1][0], s0l + 16, 64);
  unsigned d1 = __shfl(pks[2*ks+1][1], s0l + 16, 64);
  uint4v u;
  u[0] = hi5 ? b0 : a0;  u[1] = hi5 ? b1 : a1;
  u[2] = hi5 ? d0 : c0;  u[3] = hi5 ? d1 : c1;
  return __builtin_bit_cast(bf16x8, u);
}

#define PHASE_SYNC() do {                                                   \
    asm volatile("s_waitcnt lgkmcnt(0)" ::: "memory");                      \
    __builtin_amdgcn_s_barrier();                                           \
    if (item + 2 < nitems) {                                                \
      stage(item + 2);                                                      \
      asm volatile("s_waitcnt vmcnt(8)" ::: "memory");                      \
    } else {                                                                \
      asm volatile("s_waitcnt vmcnt(0)" ::: "memory");                      \
    }                                                                       \
    __builtin_amdgcn_s_barrier();                                           \
    ++item;                                                                 \
  } while (0)

// Grid (NG, 32): blockIdx.x = feature group -> linear bid % 8 == group % 8 pins each
// group's weight stream to one XCD's L2 (R4's only clearly-positive effect, FETCH 63->22MB).
__global__ __launch_bounds__(256, 2) void nam_mfma(
    const float* __restrict__ xT, const int* __restrict__ a,
    const float* __restrict__ W1, const float* __restrict__ b1,
    const float* __restrict__ b2, const float* __restrict__ b3, const float* __restrict__ b4,
    const float* __restrict__ wv, const float* __restrict__ cb,
    const __bf16* __restrict__ wb,
    float* __restrict__ pbb, float* __restrict__ py) {
  __shared__ __align__(1024) __bf16 wlds[2][H_ * H_];   // 2 x 32KB double buffer

  const int tid = threadIdx.x;
  const int l  = tid & 63;
  const int lc = l & 15, g = l >> 4;
  const int by = blockIdx.x;                            // feature group (XCD-pinned)
  const int rw = blockIdx.y * 128 + (tid >> 6) * 32;    // wave's 32-row base (4 waves)
  const int f0 = (by * F_) / NG, f1 = ((by + 1) * F_) / NG;
  const int nitems = 3 * (f1 - f0);

  const int row0 = rw + lc, row1 = rw + 16 + lc;
  const int ta0 = a[row0], ta1 = a[row1];
  const int s0l = lc + ((l & 16) << 1);
  const bool hi5 = (l & 32) != 0;

  f32x4 acc[8][2], bbsum[8][2];
  unsigned pk[2][8][2];
  const f32x4 z = {0.f, 0.f, 0.f, 0.f};
  #pragma unroll
  for (int mt = 0; mt < 8; ++mt) { bbsum[mt][0] = z; bbsum[mt][1] = z; }
  float ysum0 = 0.f, ysum1 = 0.f;

  auto stage = [&](int it) {
    const char* gsrc = (const char*)(wb + (size_t)(f0 * 3 + it) * (H_ * H_));
    char* ldst = (char*)&wlds[it & 1][0];
    #pragma unroll
    for (int r = 0; r < 8; ++r) {
      int off = (tid + 256 * r) * 16;
      __builtin_amdgcn_global_load_lds(
          (const __attribute__((address_space(1))) void*)(gsrc + off),
          (__attribute__((address_space(3))) void*)(ldst + off), 16, 0, 0);
    }
  };

  stage(0); stage(1);
  asm volatile("s_waitcnt vmcnt(8)" ::: "memory");
  __builtin_amdgcn_s_barrier();

  int item = 0;
  for (int fi = f0; fi < f1; ++fi) {
    // ================= phase 0: GEMM2 (h2 = elu(h1 W2 + b2)); h1 built on the fly =========
    {
      const __bf16* buf = wlds[item & 1];
      #pragma unroll
      for (int mt = 0; mt < 8; ++mt) { acc[mt][0] = z; acc[mt][1] = z; }
      const float* w1p = W1 + (size_t)fi * H_;
      const float* b1p = b1 + (size_t)fi * H_;
      float xs0 = xT[(size_t)fi * B_ + row0];
      float xs1 = xT[(size_t)fi * B_ + row1];
      #pragma unroll
      for (int ks = 0; ks < 4; ++ks) {
        int k0 = ks * 32 + 8 * g;
        f32x4 wa  = *(const f32x4*)(w1p + k0);
        f32x4 wb2 = *(const f32x4*)(w1p + k0 + 4);
        f32x4 ba  = *(const f32x4*)(b1p + k0);
        f32x4 bb2 = *(const f32x4*)(b1p + k0 + 4);
        bf16x8 bf0, bf1;
        #pragma unroll
        for (int e = 0; e < 4; ++e) {
          bf0[e]     = (__bf16)el(xs0 * wa[e]  + ba[e]);
          bf0[e + 4] = (__bf16)el(xs0 * wb2[e] + bb2[e]);
          bf1[e]     = (__bf16)el(xs1 * wa[e]  + ba[e]);
          bf1[e + 4] = (__bf16)el(xs1 * wb2[e] + bb2[e]);
        }
        #pragma unroll
        for (int mt = 0; mt < 8; ++mt) {
          bf16x8 av = lda(buf, mt, ks, lc, g);
          acc[mt][0] = __builtin_amdgcn_mfma_f32_16x16x32_bf16(av, bf0, acc[mt][0], 0, 0, 0);
          acc[mt][1] = __builtin_amdgcn_mfma_f32_16x16x32_bf16(av, bf1, acc[mt][1], 0, 0, 0);
        }
      }
      const float* bp = b2 + (size_t)fi * H_;
      #pragma unroll
      for (int mt = 0; mt < 8; ++mt) {
        f32x4 bia = *(const f32x4*)(bp + mt * 16 + 4 * g);
        #pragma unroll
        for (int nt = 0; nt < 2; ++nt) {
          f32x4 t = acc[mt][nt];
          float t0 = el(t[0] + bia[0]), t1 = el(t[1] + bia[1]);
          float t2 = el(t[2] + bia[2]), t3 = el(t[3] + bia[3]);
          pk[nt][mt][0] = pkpair(t0, t1);
          pk[nt][mt][1] = pkpair(t2, t3);
        }
      }
    }
    PHASE_SYNC();
    // ================= phase 1: GEMM3 (h3 = elu(h2 W3 + b3)) ==============================
    {
      const __bf16* buf = wlds[item & 1];
      #pragma unroll
      for (int mt = 0; mt < 8; ++mt) { acc[mt][0] = z; acc[mt][1] = z; }
      #pragma unroll
      for (int ks = 0; ks < 4; ++ks) {
        bf16x8 bf0 = exch(pk[0], ks, s0l, hi5);
        bf16x8 bf1 = exch(pk[1], ks, s0l, hi5);
        #pragma unroll
        for (int mt = 0; mt < 8; ++mt) {
          bf16x8 av = lda(buf, mt, ks, lc, g);
          acc[mt][0] = __builtin_amdgcn_mfma_f32_16x16x32_bf16(av, bf0, acc[mt][0], 0, 0, 0);
          acc[mt][1] = __builtin_amdgcn_mfma_f32_16x16x32_bf16(av, bf1, acc[mt][1], 0, 0, 0);
        }
      }
      const float* bp = b3 + (size_t)fi * H_;
      #pragma unroll
      for (int mt = 0; mt < 8; ++mt) {
        f32x4 bia = *(const f32x4*)(bp + mt * 16 + 4 * g);
        #pragma unroll
        for (int nt = 0; nt < 2; ++nt) {
          f32x4 t = acc[mt][nt];
          float t0 = el(t[0] + bia[0]), t1 = el(t[1] + bia[1]);
          float t2 = el(t[2] + bia[2]), t3 = el(t[3] + bia[3]);
          pk[nt][mt][0] = pkpair(t0, t1);
          pk[nt][mt][1] = pkpair(t2, t3);
        }
      }
    }
    PHASE_SYNC();
    // ================= phase 2: GEMM4 (bb = h3 W4 + b4, no elu) + heads ===================
    {
      const __bf16* buf = wlds[item & 1];
      #pragma unroll
      for (int mt = 0; mt < 8; ++mt) { acc[mt][0] = z; acc[mt][1] = z; }
      #pragma unroll
      for (int ks = 0; ks < 4; ++ks) {
        bf16x8 bf0 = exch(pk[0], ks, s0l, hi5);
        bf16x8 bf1 = exch(pk[1], ks, s0l, hi5);
        #pragma unroll
        for (int mt = 0; mt < 8; ++mt) {
          bf16x8 av = lda(buf, mt, ks, lc, g);
          acc[mt][0] = __builtin_amdgcn_mfma_f32_16x16x32_bf16(av, bf0, acc[mt][0], 0, 0, 0);
          acc[mt][1] = __builtin_amdgcn_mfma_f32_16x16x32_bf16(av, bf1, acc[mt][1], 0, 0, 0);
        }
      }
      const float* b4p = b4 + (size_t)fi * H_;
      const float* wv0 = wv + (size_t)(fi * 2 + ta0) * H_;
      const float* wv1 = wv + (size_t)(fi * 2 + ta1) * H_;
      float yd0 = 0.f, yd1 = 0.f;
      #pragma unroll
      for (int mt = 0; mt < 8; ++mt) {
        int n = mt * 16 + 4 * g;
        f32x4 bia = *(const f32x4*)(b4p + n);
        f32x4 v0 = acc[mt][0] + bia;
        f32x4 v1 = acc[mt][1] + bia;
        bbsum[mt][0] += v0;
        bbsum[mt][1] += v1;
        f32x4 wa = *(const f32x4*)(wv0 + n);
        f32x4 wc = *(const f32x4*)(wv1 + n);
        yd0 += v0[0]*wa[0] + v0[1]*wa[1] + v0[2]*wa[2] + v0[3]*wa[3];
        yd1 += v1[0]*wc[0] + v1[1]*wc[1] + v1[2]*wc[2] + v1[3]*wc[3];
      }
      ysum0 += yd0 + (g == 0 ? cb[fi * 2 + ta0] : 0.f);
      ysum1 += yd1 + (g == 0 ? cb[fi * 2 + ta1] : 0.f);
    }
    PHASE_SYNC();
  }

  // ---- partial stores (no atomics): pbb[by][row][col], py[by][row]
  #pragma unroll
  for (int mt = 0; mt < 8; ++mt) {
    int n = mt * 16 + 4 * g;
    *(f32x4*)(pbb + ((size_t)by * B_ + row0) * H_ + n) = bbsum[mt][0];
    *(f32x4*)(pbb + ((size_t)by * B_ + row1) * H_ + n) = bbsum[mt][1];
  }
  float y0 = ysum0 + __shfl_xor(ysum0, 16, 64); y0 += __shfl_xor(y0, 32, 64);
  float y1 = ysum1 + __shfl_xor(ysum1, 16, 64); y1 += __shfl_xor(y1, 32, 64);
  if (g == 0) {
    py[by * B_ + row0] = y0;
    py[by * B_ + row1] = y1;
  }
}

// ================= final reduction over the NG feature groups (vectorized) ================
__global__ __launch_bounds__(256) void reduce_out(const float* __restrict__ pbb,
                                                  const float* __restrict__ py,
                                                  float* __restrict__ out) {
  const int base = (blockIdx.x * 256 + threadIdx.x) * 4;
  f32x4 s = {0.f, 0.f, 0.f, 0.f};
  if (base < B_ * H_) {
    #pragma unroll
    for (int g = 0; g < NG; ++g) s += *(const f32x4*)(pbb + (size_t)g * (B_ * H_) + base);
  } else {
    const int b = base - B_ * H_;
    #pragma unroll
    for (int g = 0; g < NG; ++g) s += *(const f32x4*)(py + g * B_ + b);
  }
  *(f32x4*)(out + base) = s;
}

extern "C" void kernel_launch(void* const* d_in, const int* in_sizes, int n_in,
                              void* d_out, int out_size, void* d_ws, size_t ws_size,
                              hipStream_t stream) {
  const float* x   = (const float*)d_in[0];
  const int*   aa  = (const int*)d_in[1];
  const float* W1  = (const float*)d_in[2];
  const float* b1  = (const float*)d_in[3];
  const float* W2  = (const float*)d_in[4];
  const float* b2  = (const float*)d_in[5];
  const float* W3  = (const float*)d_in[6];
  const float* b3  = (const float*)d_in[7];
  const float* W4  = (const float*)d_in[8];
  const float* b4  = (const float*)d_in[9];
  const float* Wh1 = (const float*)d_in[10];
  const float* bh1 = (const float*)d_in[11];
  const float* Wh2 = (const float*)d_in[12];
  const float* bh2 = (const float*)d_in[13];
  float* out = (float*)d_out;

  char* ws = (char*)d_ws;
  float*  wv  = (float*)(ws + 0);              // 102,400 B
  float*  cbp = (float*)(ws + 102400);         // 800 B
  __bf16* wbp = (__bf16*)(ws + 103424);        // 9,830,400 B
  float*  xT  = (float*)(ws + 9933824);        // 1,638,400 B
  float*  py  = (float*)(ws + 11572224);       // 262,144 B
  float*  pbb = (float*)(ws + 11834368);       // 33,554,432 B

  prep<<<dim3(516), dim3(256), 0, stream>>>(W2, W3, W4, Wh1, bh1, Wh2, bh2, x,
                                            wbp, wv, cbp, xT);
  nam_mfma<<<dim3(NG, B_ / 128), dim3(256), 0, stream>>>(
      xT, aa, W1, b1, b2, b3, b4, wv, cbp, wbp, pbb, py);
  reduce_out<<<dim3((B_ * H_ + B_) / 1024), dim3(256), 0, stream>>>(pbb, py, out);
}